// Round 1
// baseline (3217.735 us; speedup 1.0000x reference)
//
#include <hip/hip_runtime.h>
#include <math.h>

#define BS    65536
#define TT    31
#define BIN   4
#define FEA   9
#define HID   128
#define VOCAB 19
#define NC    40
#define INSZ  133   // TT*BIN + FEA

// Prep: WT[k][i] = W_hh[i][k] (transposed for contiguous scalar loads over i),
//       WP[p][i][j] = W_ih[i][4p+j] (16B-aligned float4 gather per (p,i)).
__global__ void prep_kernel(const float* __restrict__ W_ih,
                            const float* __restrict__ W_hh,
                            float* __restrict__ WT,
                            float* __restrict__ WP) {
    int n = blockIdx.x * blockDim.x + threadIdx.x;
    if (n < HID * HID) {
        int i = n >> 7, k = n & (HID - 1);
        WT[k * HID + i] = W_hh[i * HID + k];
    }
    if (n < TT * HID * BIN) {
        int j = n & 3, i = (n >> 2) & (HID - 1), p = n >> 9;
        WP[n] = W_ih[i * INSZ + BIN * p + j];
    }
}

// One wave (64 lanes) per block; lane = batch element. h,z in VGPRs.
// LDS buf: [128][64] matvec staging, overlaid later by softmax scratch
// (l_tok @0, g_tok @1216, l_c @2432, g_c @4992; all <= 8192 floats).
// Single-wave block => no __syncthreads needed (same-lane LDS columns only).
__launch_bounds__(64, 1)
__global__ void decode_kernel(const float* __restrict__ x,
                              const float* __restrict__ ntok,
                              const float* __restrict__ ncn,
                              const float* __restrict__ W_ih,
                              const float* __restrict__ b_ih,
                              const float* __restrict__ b_hh,
                              const float* __restrict__ W_out,
                              const float* __restrict__ b_out,
                              const float* __restrict__ W_c,
                              const float* __restrict__ b_c,
                              const float* __restrict__ WT,
                              const float* __restrict__ WP,
                              float* __restrict__ out) {
    __shared__ float buf[8192];   // 32 KB -> 4 blocks/CU
    const int lane = threadIdx.x;
    const int b = blockIdx.x * 64 + lane;

    float* out_seq = out;                 // [BS][TT] as float
    float* out_cv  = out + BS * TT;       // [BS][TT]
    float* out_lp  = out + 2 * BS * TT;   // [BS]

    // init outputs (harness poisons d_out each call)
    #pragma unroll
    for (int tt = 0; tt < TT; ++tt) {
        out_seq[b * TT + tt] = -1.0f;
        out_cv[b * TT + tt]  = 0.0f;
    }

    float h[HID], z[HID];
    // z = b_ih + b_hh + x-part of W_ih projection; h = 0
    float xv[FEA];
    #pragma unroll
    for (int f = 0; f < FEA; ++f) xv[f] = x[b * FEA + f];
    #pragma unroll
    for (int i = 0; i < HID; ++i) {
        float a = b_ih[i] + b_hh[i];
        #pragma unroll
        for (int f = 0; f < FEA; ++f)
            a = fmaf(xv[f], W_ih[i * INSZ + TT * BIN + f], a);
        z[i] = a;
        h[i] = 0.0f;
    }
    // zero matvec staging so t=0 can skip the (h=0) matvec
    #pragma unroll
    for (int i = 0; i < HID; ++i) buf[i * 64 + lane] = 0.0f;

    unsigned long long stk = 0ULL;  // packed preorder stack, 6 bits/slot (sp<=5)
    int sp = 0, pos = 0;
    bool active = true;
    float lp_sum = 0.0f;

    for (int t = 0; t < TT; ++t) {
        if (__ballot(active) == 0ULL) break;   // whole-wave early exit

        // ---- matvec: buf[i][lane] = sum_k WT[k][i] * h[k] ----
        if (t > 0) {
            for (int ib = 0; ib < HID; ib += 16) {   // dynamic loop
                float acc[16];
                #pragma unroll
                for (int it = 0; it < 16; ++it) acc[it] = 0.0f;
                #pragma unroll
                for (int k = 0; k < HID; ++k) {
                    const float hk = h[k];
                    const float* w = (const float*)__builtin_assume_aligned(
                        WT + (size_t)k * HID + ib, 64);
                    #pragma unroll
                    for (int it = 0; it < 16; ++it)
                        acc[it] = fmaf(w[it], hk, acc[it]);
                }
                #pragma unroll
                for (int it = 0; it < 16; ++it)
                    buf[(ib + it) * 64 + lane] = acc[it];
            }
        }

        const int p = (pos < 0) ? 0 : (pos > TT - 1 ? TT - 1 : pos);
        const bool at_max = (p >= 15);   // depth_tab[p] >= 4

        // ---- h = tanh(z + matvec), gated by active ----
        #pragma unroll
        for (int i = 0; i < HID; ++i) {
            float a = z[i] + buf[i * 64 + lane];
            float hn = tanhf(a);
            h[i] = active ? hn : h[i];
        }

        // ---- token head: logits, mask, gumbel, log_softmax, argmax ----
        float m = -INFINITY;
        for (int v = 0; v < VOCAB; ++v) {       // dynamic loop
            float acc = b_out[v];
            #pragma unroll
            for (int k = 0; k < HID; ++k)
                acc = fmaf(W_out[v * HID + k], h[k], acc);
            if (at_max && v < 6) acc = -INFINITY;
            float u = ntok[(size_t)(t * (size_t)BS + b) * VOCAB + v];
            float gg = -logf(-logf(u + 1e-9f) + 1e-9f);
            buf[v * 64 + lane] = acc;
            buf[1216 + v * 64 + lane] = gg;
            m = fmaxf(m, acc);
        }
        float s = 0.0f;
        for (int v = 0; v < VOCAB; ++v)
            s += expf(buf[v * 64 + lane] - m);
        float logs = logf(s);
        int choice = 0;
        float best = -INFINITY, lp = 0.0f;
        for (int v = 0; v < VOCAB; ++v) {
            float logp = (buf[v * 64 + lane] - m) - logs;
            float val = logp + buf[1216 + v * 64 + lane];
            bool c = val > best;                 // strict > keeps first max
            best = c ? val : best;
            choice = c ? v : choice;
            lp = c ? logp : lp;
        }
        const bool is_const = (choice == 18);

        // ---- constant head (skipped when no active lane picked CONST) ----
        float lp_c = 0.0f, c_val = 0.0f;
        if (__ballot(active && is_const) != 0ULL) {
            float mc = -INFINITY;
            for (int v = 0; v < NC; ++v) {
                float acc = b_c[v];
                #pragma unroll
                for (int k = 0; k < HID; ++k)
                    acc = fmaf(W_c[v * HID + k], h[k], acc);
                float u = ncn[(size_t)(t * (size_t)BS + b) * NC + v];
                float gg = -logf(-logf(u + 1e-9f) + 1e-9f);
                buf[2432 + v * 64 + lane] = acc;
                buf[4992 + v * 64 + lane] = gg;
                mc = fmaxf(mc, acc);
            }
            float sc = 0.0f;
            for (int v = 0; v < NC; ++v)
                sc += expf(buf[2432 + v * 64 + lane] - mc);
            float logsc = logf(sc);
            float bestc = -INFINITY;
            int cc = 0;
            for (int v = 0; v < NC; ++v) {
                float logp = (buf[2432 + v * 64 + lane] - mc) - logsc;
                float val = logp + buf[4992 + v * 64 + lane];
                bool c = val > bestc;
                bestc = c ? val : bestc;
                cc = c ? v : cc;
                lp_c = c ? logp : lp_c;
            }
            c_val = -10.0f + 0.5f * (float)cc;
        }

        // ---- outputs ----
        if (active) {
            lp_sum += lp + (is_const ? lp_c : 0.0f);
            out_seq[b * TT + p] = (float)choice;
            if (is_const) out_cv[b * TT + p] = c_val;
        }

        // ---- z += bits . W_ih[:, 4p..4p+3] (skip if no set bits) ----
        if (__ballot(active && (choice & 15)) != 0ULL) {
            float b0 = (active && (choice & 1)) ? 1.0f : 0.0f;
            float b1 = (active && (choice & 2)) ? 1.0f : 0.0f;
            float b2 = (active && (choice & 4)) ? 1.0f : 0.0f;
            float b3 = (active && (choice & 8)) ? 1.0f : 0.0f;
            const float4* wp = (const float4*)(WP + (size_t)p * HID * 4);
            #pragma unroll
            for (int i = 0; i < HID; ++i) {
                float4 w = wp[i];
                z[i] = fmaf(b0, w.x, z[i]);
                z[i] = fmaf(b1, w.y, z[i]);
                z[i] = fmaf(b2, w.z, z[i]);
                z[i] = fmaf(b3, w.w, z[i]);
            }
        }

        // ---- preorder traversal update ----
        int arity = (choice < 4) ? 2 : ((choice < 6) ? 1 : 0);
        bool push = active && (arity == 2);
        int spc = sp; if (spc > 9) spc = 9;            // pack guard (sp<=5 really)
        if (push)
            stk = (stk & ~(63ULL << (6 * spc))) |
                  ((unsigned long long)(2 * p + 2) << (6 * spc));
        int sp1 = sp + (push ? 1 : 0);
        int ti = sp1 - 1; if (ti < 0) ti = 0; if (ti > 9) ti = 9;
        int top = (int)((stk >> (6 * ti)) & 63ULL);
        bool is_leaf = (arity == 0);
        int nxt = (!is_leaf) ? (2 * p + 1) : ((sp1 > 0) ? top : -1);
        sp = (active && is_leaf) ? ((sp1 > 0) ? sp1 - 1 : 0) : sp1;
        if (nxt > TT - 1) nxt = -1;
        pos = active ? nxt : -1;
        active = active && (pos >= 0);
    }

    out_lp[b] = lp_sum;
}

extern "C" void kernel_launch(void* const* d_in, const int* in_sizes, int n_in,
                              void* d_out, int out_size, void* d_ws, size_t ws_size,
                              hipStream_t stream) {
    const float* x     = (const float*)d_in[0];
    const float* ntok  = (const float*)d_in[1];
    const float* ncn   = (const float*)d_in[2];
    const float* W_ih  = (const float*)d_in[3];
    const float* W_hh  = (const float*)d_in[4];
    const float* b_ih  = (const float*)d_in[5];
    const float* b_hh  = (const float*)d_in[6];
    const float* W_out = (const float*)d_in[7];
    const float* b_out = (const float*)d_in[8];
    const float* W_c   = (const float*)d_in[9];
    const float* b_c   = (const float*)d_in[10];
    float* out = (float*)d_out;

    float* WT = (float*)d_ws;             // 16384 floats
    float* WP = WT + HID * HID;           // 15872 floats

    hipLaunchKernelGGL(prep_kernel, dim3(64), dim3(256), 0, stream,
                       W_ih, W_hh, WT, WP);
    hipLaunchKernelGGL(decode_kernel, dim3(BS / 64), dim3(64), 0, stream,
                       x, ntok, ncn, W_ih, b_ih, b_hh,
                       W_out, b_out, W_c, b_c, WT, WP, out);
}

// Round 2
// 1242.105 us; speedup vs baseline: 2.5906x; 2.5906x over previous
//
#include <hip/hip_runtime.h>
#include <math.h>

#define BS    65536
#define TT    31
#define BIN   4
#define FEA   9
#define HID   128
#define VOCAB 19
#define NC    40
#define INSZ  133   // TT*BIN + FEA

// Prep: WT[k][i] = W_hh[i][k] (transposed: contiguous over i for scalar loads),
//       WP[p][i][j] = W_ih[i][4p+j] (float4 per (p,i)).
__global__ void prep_kernel(const float* __restrict__ W_ih,
                            const float* __restrict__ W_hh,
                            float* __restrict__ WT,
                            float* __restrict__ WP) {
    int n = blockIdx.x * blockDim.x + threadIdx.x;
    if (n < HID * HID) {
        int i = n >> 7, k = n & (HID - 1);
        WT[k * HID + i] = W_hh[i * HID + k];
    }
    if (n < TT * HID * BIN) {
        int j = n & 3, i = (n >> 2) & (HID - 1), p = n >> 9;
        WP[n] = W_ih[i * INSZ + BIN * p + j];
    }
}

// Block = 256 threads = 4 waves, covering 64 batch elements (lane = element).
// Work split by OUTPUT dim: wave w owns h-outputs [32w,32w+32), token logits
// [5w,5w+5) (w3: 4), const logits [10w,10w+10). h lives in LDS h_lds[k][lane]
// (2-way bank aliasing, free). Traversal state replicated in all 4 waves.
__launch_bounds__(256, 4)
__global__ void decode_kernel(const float* __restrict__ x,
                              const float* __restrict__ ntok,
                              const float* __restrict__ ncn,
                              const float* __restrict__ W_ih,
                              const float* __restrict__ b_ih,
                              const float* __restrict__ b_hh,
                              const float* __restrict__ W_out,
                              const float* __restrict__ b_out,
                              const float* __restrict__ W_c,
                              const float* __restrict__ b_c,
                              const float* __restrict__ WT,
                              const float* __restrict__ WP,
                              float* __restrict__ out) {
    __shared__ float h_lds[HID][64];      // 32 KB
    __shared__ float mw[4][64], sw[4][64];
    __shared__ float cvv[4][64], cl[4][64];
    __shared__ int   ci[4][64];

    const int lane = threadIdx.x & 63;
    const int w = __builtin_amdgcn_readfirstlane((int)(threadIdx.x >> 6));
    const int i0 = w * 32;                // this wave's h-output base
    const int b = blockIdx.x * 64 + lane;

    float* out_seq = out;                 // [BS][TT] as float
    float* out_cv  = out + BS * TT;       // [BS][TT]
    float* out_lp  = out + 2 * BS * TT;   // [BS]

    // init outputs cooperatively (coalesced: block owns 64*TT contiguous)
    {
        const int base = blockIdx.x * 64 * TT;
        for (int i = threadIdx.x; i < 64 * TT; i += 256) {
            out_seq[base + i] = -1.0f;
            out_cv[base + i]  = 0.0f;
        }
    }

    // z = this wave's 32 components of b_ih + b_hh + x @ W_ih[:,124:133].T
    float z[32];
    {
        float xv[FEA];
        #pragma unroll
        for (int f = 0; f < FEA; ++f) xv[f] = x[b * FEA + f];
        #pragma unroll
        for (int ii = 0; ii < 32; ++ii) {
            const int i = i0 + ii;
            float a = b_ih[i] + b_hh[i];
            #pragma unroll
            for (int f = 0; f < FEA; ++f)
                a = fmaf(xv[f], W_ih[i * INSZ + TT * BIN + f], a);
            z[ii] = a;
        }
    }

    // replicated per-lane traversal state (identical in all 4 waves)
    unsigned long long stk = 0ULL;  // packed stack, 6 bits/slot
    int sp = 0, pos = 0;
    bool active = true;
    float lp_sum = 0.0f;

    __syncthreads();

    for (int t = 0; t < TT; ++t) {
        // ---- matvec: acc[ii] = z[ii] + sum_k WT[k][i0+ii] * h_lds[k][lane]
        float acc[32];
        #pragma unroll
        for (int ii = 0; ii < 32; ++ii) acc[ii] = z[ii];
        if (t > 0) {
            #pragma unroll 4
            for (int k = 0; k < HID; ++k) {
                const float hk = h_lds[k][lane];
                const float* wr = WT + (size_t)k * HID + i0;
                #pragma unroll
                for (int ii = 0; ii < 32; ++ii)
                    acc[ii] = fmaf(wr[ii], hk, acc[ii]);
            }
        }
        float hn[32];
        #pragma unroll
        for (int ii = 0; ii < 32; ++ii) hn[ii] = tanhf(acc[ii]);

        __syncthreads();                       // done reading old h
        #pragma unroll
        for (int ii = 0; ii < 32; ++ii) h_lds[i0 + ii][lane] = hn[ii];
        __syncthreads();                       // h_lds = h_t for all waves

        const int p = (pos < 0) ? 0 : (pos > TT - 1 ? TT - 1 : pos);
        const bool at_max = (p >= 15);         // depth >= 4

        // ---- token head: this wave's v in [5w, 5w+nv) ----
        const int v0 = w * 5;
        const int nv = (w == 3) ? 4 : 5;
        float lg[5], gb[5];
        float m_loc = -INFINITY;
        {
            float a[5];
            #pragma unroll
            for (int j = 0; j < 5; ++j) a[j] = (j < nv) ? b_out[v0 + j] : 0.0f;
            #pragma unroll 4
            for (int k = 0; k < HID; ++k) {
                const float hk = h_lds[k][lane];
                #pragma unroll
                for (int j = 0; j < 5; ++j)
                    if (j < nv)
                        a[j] = fmaf(W_out[(v0 + j) * HID + k], hk, a[j]);
            }
            #pragma unroll
            for (int j = 0; j < 5; ++j) {
                if (j >= nv) { lg[j] = -INFINITY; gb[j] = 0.0f; continue; }
                float av = a[j];
                if (at_max && (v0 + j) < 6) av = -INFINITY;
                lg[j] = av;
                m_loc = fmaxf(m_loc, av);
                float u = ntok[((size_t)t * BS + b) * VOCAB + v0 + j];
                gb[j] = -logf(-logf(u + 1e-9f) + 1e-9f);
            }
        }
        float s_loc = 0.0f;
        if (m_loc != -INFINITY) {
            #pragma unroll
            for (int j = 0; j < 5; ++j)
                if (j < nv && lg[j] != -INFINITY) s_loc += expf(lg[j] - m_loc);
        }
        mw[w][lane] = m_loc;
        sw[w][lane] = s_loc;
        __syncthreads();

        // redundant cross-wave logsumexp combine (all waves, identical)
        float m = -INFINITY;
        #pragma unroll
        for (int q = 0; q < 4; ++q) m = fmaxf(m, mw[q][lane]);
        float s = 0.0f;
        #pragma unroll
        for (int q = 0; q < 4; ++q) {
            const float mq = mw[q][lane];
            if (mq != -INFINITY) s += sw[q][lane] * expf(mq - m);
        }
        const float logs = logf(s);

        // local argmax of logp + g  (reference-faithful value ordering)
        float bv = -INFINITY, blp = 0.0f;
        int bi = v0;
        #pragma unroll
        for (int j = 0; j < 5; ++j) {
            if (j >= nv) continue;
            const float logp = (lg[j] - m) - logs;
            const float val = logp + gb[j];
            if (val > bv) { bv = val; bi = v0 + j; blp = logp; }
        }
        cvv[w][lane] = bv; ci[w][lane] = bi; cl[w][lane] = blp;
        __syncthreads();

        // global combine (ascending wave order = first-index-wins)
        float best = cvv[0][lane], lp = cl[0][lane];
        int choice = ci[0][lane];
        #pragma unroll
        for (int q = 1; q < 4; ++q) {
            const float qv = cvv[q][lane];
            if (qv > best) { best = qv; choice = ci[q][lane]; lp = cl[q][lane]; }
        }
        const bool is_const = (choice == 18);

        // ---- constant head (block-wide conditional; ballot identical per wave)
        float lp_c = 0.0f, c_val = 0.0f;
        if (__ballot(active && is_const) != 0ULL) {
            __syncthreads();                   // mw/cand arrays safe to reuse
            const int c0 = w * 10;
            float lgc[10], gbc[10];
            float mc_loc = -INFINITY;
            {
                float a[10];
                #pragma unroll
                for (int j = 0; j < 10; ++j) a[j] = b_c[c0 + j];
                #pragma unroll 4
                for (int k = 0; k < HID; ++k) {
                    const float hk = h_lds[k][lane];
                    #pragma unroll
                    for (int j = 0; j < 10; ++j)
                        a[j] = fmaf(W_c[(c0 + j) * HID + k], hk, a[j]);
                }
                #pragma unroll
                for (int j = 0; j < 10; ++j) {
                    lgc[j] = a[j];
                    mc_loc = fmaxf(mc_loc, a[j]);
                    float u = ncn[((size_t)t * BS + b) * NC + c0 + j];
                    gbc[j] = -logf(-logf(u + 1e-9f) + 1e-9f);
                }
            }
            float sc_loc = 0.0f;
            #pragma unroll
            for (int j = 0; j < 10; ++j) sc_loc += expf(lgc[j] - mc_loc);
            mw[w][lane] = mc_loc;
            sw[w][lane] = sc_loc;
            __syncthreads();

            float mc = -INFINITY;
            #pragma unroll
            for (int q = 0; q < 4; ++q) mc = fmaxf(mc, mw[q][lane]);
            float sc = 0.0f;
            #pragma unroll
            for (int q = 0; q < 4; ++q) sc += sw[q][lane] * expf(mw[q][lane] - mc);
            const float logsc = logf(sc);

            float bvc = -INFINITY, blpc = 0.0f;
            int bic = c0;
            #pragma unroll
            for (int j = 0; j < 10; ++j) {
                const float logp = (lgc[j] - mc) - logsc;
                const float val = logp + gbc[j];
                if (val > bvc) { bvc = val; bic = c0 + j; blpc = logp; }
            }
            cvv[w][lane] = bvc; ci[w][lane] = bic; cl[w][lane] = blpc;
            __syncthreads();

            float bestc = cvv[0][lane]; int cc = ci[0][lane]; lp_c = cl[0][lane];
            #pragma unroll
            for (int q = 1; q < 4; ++q) {
                const float qv = cvv[q][lane];
                if (qv > bestc) { bestc = qv; cc = ci[q][lane]; lp_c = cl[q][lane]; }
            }
            c_val = -10.0f + 0.5f * (float)cc;
        }

        // ---- outputs (wave 0 only; state identical in all waves) ----
        lp_sum += active ? (lp + (is_const ? lp_c : 0.0f)) : 0.0f;
        if (w == 0 && active) {
            out_seq[b * TT + p] = (float)choice;
            if (is_const) out_cv[b * TT + p] = c_val;
        }

        // ---- z += bits . W_ih[:, 4p..4p+3] for this wave's i-range ----
        if (__ballot(active && (choice & 15)) != 0ULL) {
            const float b0 = (active && (choice & 1)) ? 1.0f : 0.0f;
            const float b1 = (active && (choice & 2)) ? 1.0f : 0.0f;
            const float b2 = (active && (choice & 4)) ? 1.0f : 0.0f;
            const float b3 = (active && (choice & 8)) ? 1.0f : 0.0f;
            const float4* wp = (const float4*)WP + (size_t)p * HID + i0;
            #pragma unroll
            for (int ii = 0; ii < 32; ++ii) {
                const float4 wv = wp[ii];
                z[ii] = fmaf(b0, wv.x, z[ii]);
                z[ii] = fmaf(b1, wv.y, z[ii]);
                z[ii] = fmaf(b2, wv.z, z[ii]);
                z[ii] = fmaf(b3, wv.w, z[ii]);
            }
        }

        // ---- preorder traversal update (replicated) ----
        const int arity = (choice < 4) ? 2 : ((choice < 6) ? 1 : 0);
        const bool push = active && (arity == 2);
        int spc = sp; if (spc > 9) spc = 9;
        if (push)
            stk = (stk & ~(63ULL << (6 * spc))) |
                  ((unsigned long long)(2 * p + 2) << (6 * spc));
        const int sp1 = sp + (push ? 1 : 0);
        int ti = sp1 - 1; if (ti < 0) ti = 0; if (ti > 9) ti = 9;
        const int top = (int)((stk >> (6 * ti)) & 63ULL);
        const bool is_leaf = (arity == 0);
        int nxt = (!is_leaf) ? (2 * p + 1) : ((sp1 > 0) ? top : -1);
        sp = (active && is_leaf) ? ((sp1 > 0) ? sp1 - 1 : 0) : sp1;
        if (nxt > TT - 1) nxt = -1;
        pos = active ? nxt : -1;
        active = active && (pos >= 0);

        if (__ballot(active) == 0ULL) break;   // identical in all waves
    }

    if (w == 0) out_lp[b] = lp_sum;
}

extern "C" void kernel_launch(void* const* d_in, const int* in_sizes, int n_in,
                              void* d_out, int out_size, void* d_ws, size_t ws_size,
                              hipStream_t stream) {
    const float* x     = (const float*)d_in[0];
    const float* ntok  = (const float*)d_in[1];
    const float* ncn   = (const float*)d_in[2];
    const float* W_ih  = (const float*)d_in[3];
    const float* W_hh  = (const float*)d_in[4];
    const float* b_ih  = (const float*)d_in[5];
    const float* b_hh  = (const float*)d_in[6];
    const float* W_out = (const float*)d_in[7];
    const float* b_out = (const float*)d_in[8];
    const float* W_c   = (const float*)d_in[9];
    const float* b_c   = (const float*)d_in[10];
    float* out = (float*)d_out;

    float* WT = (float*)d_ws;             // 16384 floats
    float* WP = WT + HID * HID;           // 15872 floats

    hipLaunchKernelGGL(prep_kernel, dim3(64), dim3(256), 0, stream,
                       W_ih, W_hh, WT, WP);
    hipLaunchKernelGGL(decode_kernel, dim3(BS / 64), dim3(256), 0, stream,
                       x, ntok, ncn, W_ih, b_ih, b_hh,
                       W_out, b_out, W_c, b_c, WT, WP, out);
}